// Round 9
// baseline (609.598 us; speedup 1.0000x reference)
//
#include <hip/hip_runtime.h>

typedef unsigned short ushort_t;
typedef unsigned int uint_t;
typedef __attribute__((ext_vector_type(8))) short short8;
typedef __attribute__((ext_vector_type(4))) float f32x4;
typedef __attribute__((ext_vector_type(4))) int i32x4;
typedef __attribute__((ext_vector_type(4))) uint_t u32x4;

#define LRELU_SLOPE 0.2f

static __device__ __forceinline__ float bf2f(ushort_t h) {
    uint_t u = ((uint_t)h) << 16;
    return __builtin_bit_cast(float, u);
}
static __device__ __forceinline__ ushort_t f2bf(float f) {
    uint_t u = __builtin_bit_cast(uint_t, f);
    uint_t r = (u + 0x7fffu + ((u >> 16) & 1u)) >> 16;
    return (ushort_t)r;
}

// split 4 f32 into bf16 hi + bf16 residual
static __device__ __forceinline__ void split4(float4 x, uint2& hi, uint2& lo) {
    ushort_t h0 = f2bf(x.x), h1 = f2bf(x.y), h2 = f2bf(x.z), h3 = f2bf(x.w);
    hi.x = (uint_t)h0 | ((uint_t)h1 << 16);
    hi.y = (uint_t)h2 | ((uint_t)h3 << 16);
    float r0 = x.x - bf2f(h0), r1 = x.y - bf2f(h1);
    float r2 = x.z - bf2f(h2), r3 = x.w - bf2f(h3);
    lo.x = (uint_t)f2bf(r0) | ((uint_t)f2bf(r1) << 16);
    lo.y = (uint_t)f2bf(r2) | ((uint_t)f2bf(r3) << 16);
}

// ---------------------------------------------------------------------------
// K1: whT[o][i] = sum_k W[o][k]*h[i][k] + Wb[o]  (bf16 whT, 256 x 8192)
//     + s_src/s_dst f32. Unchanged from r8 (passed; not yet the bottleneck).
// ---------------------------------------------------------------------------
__launch_bounds__(256, 2)
__global__ void k1_gemm(const float* __restrict__ h, const float* __restrict__ W,
                        const float* __restrict__ Wb, const float* __restrict__ aw,
                        ushort_t* __restrict__ whT, float* __restrict__ s_src,
                        float* __restrict__ s_dst) {
    __shared__ __align__(16) ushort_t aHi[256 * 40], aLo[256 * 40];
    __shared__ __align__(16) ushort_t bHi[32 * 40], bLo[32 * 40];
    __shared__ float redLds[2][4][32];

    const int t = threadIdx.x;
    const int wv = t >> 6, ln = t & 63;
    const int i0 = blockIdx.x * 32;
    const int srow = t >> 3, sch = t & 7;

    f32x4 acc[4][2];
#pragma unroll
    for (int mt = 0; mt < 4; ++mt)
#pragma unroll
        for (int nt = 0; nt < 2; ++nt) acc[mt][nt] = (f32x4){0.f, 0.f, 0.f, 0.f};

    for (int k0 = 0; k0 < 512; k0 += 32) {
        __syncthreads();
#pragma unroll
        for (int r = 0; r < 8; ++r) {
            float4 x = *(const float4*)(W + (size_t)(r * 32 + srow) * 512 + k0 + sch * 4);
            uint2 hi, lo;
            split4(x, hi, lo);
            *(uint2*)(aHi + (r * 32 + srow) * 40 + sch * 4) = hi;
            *(uint2*)(aLo + (r * 32 + srow) * 40 + sch * 4) = lo;
        }
        {
            float4 x = *(const float4*)(h + (size_t)(i0 + srow) * 512 + k0 + sch * 4);
            uint2 hi, lo;
            split4(x, hi, lo);
            *(uint2*)(bHi + srow * 40 + sch * 4) = hi;
            *(uint2*)(bLo + srow * 40 + sch * 4) = lo;
        }
        __syncthreads();
        {
            short8 bh[2], bl[2];
#pragma unroll
            for (int nt = 0; nt < 2; ++nt) {
                const int boff = (nt * 16 + (ln & 15)) * 40 + (ln >> 4) * 8;
                bh[nt] = *(const short8*)(bHi + boff);
                bl[nt] = *(const short8*)(bLo + boff);
            }
#pragma unroll
            for (int mt = 0; mt < 4; ++mt) {
                const int aoff = (wv * 64 + mt * 16 + (ln & 15)) * 40 + (ln >> 4) * 8;
                short8 ah = *(const short8*)(aHi + aoff);
                short8 al = *(const short8*)(aLo + aoff);
#pragma unroll
                for (int nt = 0; nt < 2; ++nt) {
                    acc[mt][nt] = __builtin_amdgcn_mfma_f32_16x16x32_bf16(ah, bh[nt], acc[mt][nt], 0, 0, 0);
                    acc[mt][nt] = __builtin_amdgcn_mfma_f32_16x16x32_bf16(ah, bl[nt], acc[mt][nt], 0, 0, 0);
                    acc[mt][nt] = __builtin_amdgcn_mfma_f32_16x16x32_bf16(al, bh[nt], acc[mt][nt], 0, 0, 0);
                }
            }
        }
    }

    float psrc[2] = {0.f, 0.f}, pdst[2] = {0.f, 0.f};
#pragma unroll
    for (int mt = 0; mt < 4; ++mt) {
#pragma unroll
        for (int r = 0; r < 4; ++r) {
            const int o = wv * 64 + mt * 16 + (ln >> 4) * 4 + r;
            const float wbv = Wb[o];
            const float as = aw[o];
            const float ad = aw[256 + o];
#pragma unroll
            for (int nt = 0; nt < 2; ++nt) {
                const float v = acc[mt][nt][r] + wbv;
                psrc[nt] += v * as;
                pdst[nt] += v * ad;
                const int i = i0 + nt * 16 + (ln & 15);
                whT[(size_t)o * 8192 + i] = f2bf(v);
            }
        }
    }
#pragma unroll
    for (int off = 16; off < 64; off <<= 1) {
#pragma unroll
        for (int nt = 0; nt < 2; ++nt) {
            psrc[nt] += __shfl_xor(psrc[nt], off, 64);
            pdst[nt] += __shfl_xor(pdst[nt], off, 64);
        }
    }
    if (ln < 16) {
#pragma unroll
        for (int nt = 0; nt < 2; ++nt) {
            redLds[0][wv][nt * 16 + ln] = psrc[nt];
            redLds[1][wv][nt * 16 + ln] = pdst[nt];
        }
    }
    __syncthreads();
    if (t < 32) {
        float s = 0.f;
#pragma unroll
        for (int w = 0; w < 4; ++w) s += redLds[0][w][t];
        s_src[i0 + t] = s;
    } else if (t < 64) {
        float s = 0.f;
#pragma unroll
        for (int w = 0; w < 4; ++w) s += redLds[1][w][t - 32];
        s_dst[i0 + t - 32] = s;
    }
}

// ---------------------------------------------------------------------------
// K2: BARRIER-FREE K-loop. grid 256 x 512 (8 waves): dq=wv&3 owns 64 d's,
// kh=wv>>2 owns a 32-j half of each 64-j tile. Each lane computes its own
// MFMA A-fragment (P values) in registers from adj/s_dst, and loads its
// B-fragment (whT) directly global->register. No LDS, no __syncthreads in
// the loop -> global prefetch stays in flight (the r8 barrier drained it).
// Epilogue (once): LDS exchange for kh-pair combine + Z, f32 out.
// ---------------------------------------------------------------------------
__launch_bounds__(512, 1)
__global__ void k2_attn(const int* __restrict__ adj, const ushort_t* __restrict__ whT,
                        const float* __restrict__ s_src, const float* __restrict__ s_dst,
                        const float* __restrict__ ab_p, float* __restrict__ out) {
    __shared__ float ex[256 * 33];  // kh-pair exchange, stride-33: conflict-free
    __shared__ float zA[32], zB[32];

    const int t = threadIdx.x;
    const int wv = t >> 6, ln = t & 63;
    const int dq = wv & 3, kh = wv >> 2;
    const int i0 = blockIdx.x * 32;
    const int row0 = ln & 15, kq = ln >> 4;

    const float ab = ab_p[0];
    const float sb0 = s_src[i0 + row0] + ab;        // row for mt=0
    const float sb1 = s_src[i0 + 16 + row0] + ab;   // row for mt=1

    // per-lane fixed offsets; j advances by 64 per iter
    const int joff = kh * 32 + kq * 8;
    const int* aBase0 = adj + (size_t)(i0 + row0) * 8192 + joff;
    const int* aBase1 = adj + (size_t)(i0 + 16 + row0) * 8192 + joff;
    const float* sBase = s_dst + joff;
    const ushort_t* wBase = whT + (size_t)(dq * 64 + row0) * 8192 + joff;

    f32x4 acc[2][4];
#pragma unroll
    for (int mt = 0; mt < 2; ++mt)
#pragma unroll
        for (int nt = 0; nt < 4; ++nt) acc[mt][nt] = (f32x4){0.f, 0.f, 0.f, 0.f};
    float z0 = 0.f, z1 = 0.f;

    // prefetch tile 0
    i32x4 A0a = *(const i32x4*)aBase0, A0b = *(const i32x4*)(aBase0 + 4);
    i32x4 A1a = *(const i32x4*)aBase1, A1b = *(const i32x4*)(aBase1 + 4);
    f32x4 Sa = *(const f32x4*)sBase, Sb = *(const f32x4*)(sBase + 4);
    short8 Bf[4];
#pragma unroll
    for (int nt = 0; nt < 4; ++nt)
        Bf[nt] = *(const short8*)(wBase + (size_t)nt * 16 * 8192);

    for (int it = 0; it < 128; ++it) {
        const int jn = (it < 127) ? (it + 1) * 64 : it * 64;
        // consume-copies
        i32x4 cA0a = A0a, cA0b = A0b, cA1a = A1a, cA1b = A1b;
        f32x4 cSa = Sa, cSb = Sb;
        short8 cB[4];
#pragma unroll
        for (int nt = 0; nt < 4; ++nt) cB[nt] = Bf[nt];
        // issue next-tile loads (no barrier ahead -> they stay in flight)
        A0a = *(const i32x4*)(aBase0 + jn);
        A0b = *(const i32x4*)(aBase0 + jn + 4);
        A1a = *(const i32x4*)(aBase1 + jn);
        A1b = *(const i32x4*)(aBase1 + jn + 4);
        Sa = *(const f32x4*)(sBase + jn);
        Sb = *(const f32x4*)(sBase + jn + 4);
#pragma unroll
        for (int nt = 0; nt < 4; ++nt)
            Bf[nt] = *(const short8*)(wBase + (size_t)nt * 16 * 8192 + jn);

        // ---- A-fragments in registers: p = adj ? exp(min(lrelu(s),60)) : 0
        short8 af0, af1;
#pragma unroll
        for (int e = 0; e < 8; ++e) {
            const float sd = (e < 4) ? cSa[e] : cSb[e - 4];
            const int a0 = (e < 4) ? cA0a[e] : cA0b[e - 4];
            const int a1 = (e < 4) ? cA1a[e] : cA1b[e - 4];
            float t0 = sb0 + sd;
            float t1 = sb1 + sd;
            t0 = fminf(fmaxf(t0, LRELU_SLOPE * t0), 60.f);
            t1 = fminf(fmaxf(t1, LRELU_SLOPE * t1), 60.f);
            float p0 = (a0 > 0) ? __expf(t0) : 0.f;
            float p1 = (a1 > 0) ? __expf(t1) : 0.f;
            z0 += p0;
            z1 += p1;
            af0[e] = (short)f2bf(p0);
            af1[e] = (short)f2bf(p1);
        }
        // ---- MFMA ----
#pragma unroll
        for (int nt = 0; nt < 4; ++nt) {
            acc[0][nt] = __builtin_amdgcn_mfma_f32_16x16x32_bf16(af0, cB[nt], acc[0][nt], 0, 0, 0);
            acc[1][nt] = __builtin_amdgcn_mfma_f32_16x16x32_bf16(af1, cB[nt], acc[1][nt], 0, 0, 0);
        }
    }

    // ---- epilogue ----
    // Z: reduce over kq groups (lanes ^16, ^32); all dq waves computed the
    // same p's -> use dq==0's kh pair only.
    z0 += __shfl_xor(z0, 16, 64);
    z0 += __shfl_xor(z0, 32, 64);
    z1 += __shfl_xor(z1, 16, 64);
    z1 += __shfl_xor(z1, 32, 64);
    if (wv == 0 && ln < 16) {
        zA[row0] = z0;
        zA[16 + row0] = z1;
    }
    if (wv == 4 && ln < 16) {
        zB[row0] = z0;
        zB[16 + row0] = z1;
    }
    if (kh == 1) {
        float* p = ex + (dq * 64 + ln) * 33;
#pragma unroll
        for (int mt = 0; mt < 2; ++mt)
#pragma unroll
            for (int nt = 0; nt < 4; ++nt)
#pragma unroll
                for (int r = 0; r < 4; ++r) p[mt * 16 + nt * 4 + r] = acc[mt][nt][r];
    }
    __syncthreads();
    if (kh == 0) {
        const float* p = ex + (dq * 64 + ln) * 33;
#pragma unroll
        for (int mt = 0; mt < 2; ++mt)
#pragma unroll
            for (int r = 0; r < 4; ++r) {
                const int il = mt * 16 + kq * 4 + r;
                const float zinv = 1.0f / fmaxf(zA[il] + zB[il], 1e-30f);
#pragma unroll
                for (int nt = 0; nt < 4; ++nt) {
                    const int d = dq * 64 + nt * 16 + row0;
                    out[(size_t)(i0 + il) * 256 + d] =
                        (acc[mt][nt][r] + p[mt * 16 + nt * 4 + r]) * zinv;
                }
            }
    }
}

extern "C" void kernel_launch(void* const* d_in, const int* in_sizes, int n_in, void* d_out,
                              int out_size, void* d_ws, size_t ws_size, hipStream_t stream) {
    // identify inputs by flat size (validated r7/r8)
    int order[16];
    for (int i = 0; i < n_in; ++i) order[i] = i;
    for (int a = 0; a < n_in; ++a)
        for (int b = a + 1; b < n_in; ++b)
            if (in_sizes[order[b]] < in_sizes[order[a]]) {
                int tmp = order[a]; order[a] = order[b]; order[b] = tmp;
            }
    const float* ab = (const float*)d_in[order[0]];
    const float* Wb = (const float*)d_in[order[1]];
    const float* aw = (const float*)d_in[order[2]];
    const float* Ww = (const float*)d_in[order[3]];
    const float* h = (const float*)d_in[order[4]];
    const int* adj = (const int*)d_in[order[5]];

    char* ws = (char*)d_ws;
    ushort_t* whT = (ushort_t*)ws;                 // 4 MB
    float* ssrc = (float*)(ws + 4194304);          // 32 KB
    float* sdst = (float*)(ws + 4194304 + 32768);  // 32 KB

    hipLaunchKernelGGL(k1_gemm, dim3(256), dim3(256), 0, stream, h, Ww, Wb, aw, whT, ssrc, sdst);
    hipLaunchKernelGGL(k2_attn, dim3(256), dim3(512), 0, stream, adj, whT, ssrc, sdst, ab,
                       (float*)d_out);
}

// Round 10
// 443.608 us; speedup vs baseline: 1.3742x; 1.3742x over previous
//
#include <hip/hip_runtime.h>

typedef unsigned short ushort_t;
typedef unsigned int uint_t;
typedef __attribute__((ext_vector_type(8))) short short8;
typedef __attribute__((ext_vector_type(4))) float f32x4;
typedef __attribute__((ext_vector_type(4))) int i32x4;
typedef __attribute__((ext_vector_type(4))) uint_t u32x4;
typedef __attribute__((ext_vector_type(4))) ushort_t u16x4;

#define LRELU_SLOPE 0.2f

static __device__ __forceinline__ float bf2f(ushort_t h) {
    uint_t u = ((uint_t)h) << 16;
    return __builtin_bit_cast(float, u);
}
static __device__ __forceinline__ ushort_t f2bf(float f) {
    uint_t u = __builtin_bit_cast(uint_t, f);
    uint_t r = (u + 0x7fffu + ((u >> 16) & 1u)) >> 16;
    return (ushort_t)r;
}
static __device__ __forceinline__ uint4 pack8(float4 a, float4 b) {
    uint4 r;
    r.x = (uint_t)f2bf(a.x) | ((uint_t)f2bf(a.y) << 16);
    r.y = (uint_t)f2bf(a.z) | ((uint_t)f2bf(a.w) << 16);
    r.z = (uint_t)f2bf(b.x) | ((uint_t)f2bf(b.y) << 16);
    r.w = (uint_t)f2bf(b.z) | ((uint_t)f2bf(b.w) << 16);
    return r;
}

// ---------------------------------------------------------------------------
// K1: whT[o][i] = bf16(sum_k W[o][k]*h[i][k] + Wb[o]) + s_src/s_dst f32.
// Single bf16 MFMA (split-precision dropped: whT is bf16-rounded downstream
// anyway; s error ~4e-3 fits the budget). K-tile 64, 8 iters.
// grid 256 x 256 (4 waves): all 256 o, 32-wide i-tile.
// ---------------------------------------------------------------------------
__launch_bounds__(256, 2)
__global__ void k1_gemm(const float* __restrict__ h, const float* __restrict__ W,
                        const float* __restrict__ Wb, const float* __restrict__ aw,
                        ushort_t* __restrict__ whT, float* __restrict__ s_src,
                        float* __restrict__ s_dst) {
    __shared__ __align__(16) ushort_t aT[256 * 72];  // W tile [o][k], stride 144 B
    __shared__ __align__(16) ushort_t bT[32 * 72];   // h tile [i][k]
    __shared__ float redLds[2][4][32];

    const int t = threadIdx.x;
    const int wv = t >> 6, ln = t & 63;
    const int i0 = blockIdx.x * 32;
    const int srow = t >> 3, sch = t & 7;  // staging: 32 rows/round, 8 lanes/row, 8 elem
    const int row0 = ln & 15, kq = ln >> 4;

    f32x4 acc[4][2];
#pragma unroll
    for (int mt = 0; mt < 4; ++mt)
#pragma unroll
        for (int nt = 0; nt < 2; ++nt) acc[mt][nt] = (f32x4){0.f, 0.f, 0.f, 0.f};

    for (int k0 = 0; k0 < 512; k0 += 64) {
        __syncthreads();
#pragma unroll
        for (int r = 0; r < 8; ++r) {
            const float* gp = W + (size_t)(r * 32 + srow) * 512 + k0 + sch * 8;
            float4 x0 = *(const float4*)gp;
            float4 x1 = *(const float4*)(gp + 4);
            *(uint4*)(aT + (r * 32 + srow) * 72 + sch * 8) = pack8(x0, x1);
        }
        {
            const float* gp = h + (size_t)(i0 + srow) * 512 + k0 + sch * 8;
            float4 x0 = *(const float4*)gp;
            float4 x1 = *(const float4*)(gp + 4);
            *(uint4*)(bT + srow * 72 + sch * 8) = pack8(x0, x1);
        }
        __syncthreads();
#pragma unroll
        for (int ks = 0; ks < 2; ++ks) {
            short8 b[2];
#pragma unroll
            for (int nt = 0; nt < 2; ++nt)
                b[nt] = *(const short8*)(bT + (nt * 16 + row0) * 72 + ks * 32 + kq * 8);
#pragma unroll
            for (int mt = 0; mt < 4; ++mt) {
                short8 a = *(const short8*)(aT + (wv * 64 + mt * 16 + row0) * 72 + ks * 32 + kq * 8);
#pragma unroll
                for (int nt = 0; nt < 2; ++nt)
                    acc[mt][nt] = __builtin_amdgcn_mfma_f32_16x16x32_bf16(a, b[nt], acc[mt][nt], 0, 0, 0);
            }
        }
    }

    // epilogue: bias, whT bf16 store, s partials from f32 accumulators
    float psrc[2] = {0.f, 0.f}, pdst[2] = {0.f, 0.f};
#pragma unroll
    for (int mt = 0; mt < 4; ++mt) {
#pragma unroll
        for (int r = 0; r < 4; ++r) {
            const int o = wv * 64 + mt * 16 + (ln >> 4) * 4 + r;
            const float wbv = Wb[o];
            const float as = aw[o];
            const float ad = aw[256 + o];
#pragma unroll
            for (int nt = 0; nt < 2; ++nt) {
                const float v = acc[mt][nt][r] + wbv;
                psrc[nt] += v * as;
                pdst[nt] += v * ad;
                const int i = i0 + nt * 16 + (ln & 15);
                whT[(size_t)o * 8192 + i] = f2bf(v);
            }
        }
    }
#pragma unroll
    for (int off = 16; off < 64; off <<= 1) {
#pragma unroll
        for (int nt = 0; nt < 2; ++nt) {
            psrc[nt] += __shfl_xor(psrc[nt], off, 64);
            pdst[nt] += __shfl_xor(pdst[nt], off, 64);
        }
    }
    if (ln < 16) {
#pragma unroll
        for (int nt = 0; nt < 2; ++nt) {
            redLds[0][wv][nt * 16 + ln] = psrc[nt];
            redLds[1][wv][nt * 16 + ln] = pdst[nt];
        }
    }
    __syncthreads();
    if (t < 32) {
        float s = 0.f;
#pragma unroll
        for (int w = 0; w < 4; ++w) s += redLds[0][w][t];
        s_src[i0 + t] = s;
    } else if (t < 64) {
        float s = 0.f;
#pragma unroll
        for (int w = 0; w < 4; ++w) s += redLds[1][w][t - 32];
        s_dst[i0 + t - 32] = s;
    }
}

// ---------------------------------------------------------------------------
// K2: r8 structure (LDS-staged, coalesced, exp-once) + j-split for 2 blocks/CU
// barrier-drain overlap. grid (256*jsplit) x 512 thr: dq=wv&3 owns 64 d's,
// kh=wv>>2 owns a 32-j half. jsplit==2: unnormalized partials (jb0->out0,
// jb1->out1) + z partials; jsplit==1: direct normalized write (r8 path).
// ---------------------------------------------------------------------------
__launch_bounds__(512, 4)
__global__ void k2_attn(const int* __restrict__ adj, const ushort_t* __restrict__ whT,
                        const float* __restrict__ s_src, const float* __restrict__ s_dst,
                        const float* __restrict__ ab_p, float* __restrict__ out0,
                        float* __restrict__ out1, float* __restrict__ zp, int jsplit) {
    __shared__ __align__(16) ushort_t wLds[256 * 72];  // whT tile [d][j]
    __shared__ __align__(16) ushort_t pLds[32 * 72];   // p tile [i][j]
    __shared__ float zLds[32];

    const int t = threadIdx.x;
    const int wv = t >> 6, ln = t & 63;
    const int dq = wv & 3, kh = wv >> 2;
    const int split2 = (jsplit == 2);
    const int jb = split2 ? (int)(blockIdx.x & 1) : 0;
    const int ib = split2 ? (int)(blockIdx.x >> 1) : (int)blockIdx.x;
    const int i0 = ib * 32;
    const int jlen = split2 ? 4096 : 8192;
    const int jbase = jb * jlen;
    const int iters = jlen >> 6;
    const int prow = t >> 4, pjc = t & 15;  // p-compute: row 0..31, 4 j's each
    const int srow = t >> 3, sch = t & 7;   // staging: 64 rows/round, 8 lanes/row

    const float ab = ab_p[0];
    const float ssrc = s_src[i0 + prow];

    const int* aBase = adj + (size_t)(i0 + prow) * 8192 + jbase + pjc * 4;
    const float* sBase = s_dst + jbase + pjc * 4;
    const ushort_t* wBase = whT + (size_t)srow * 8192 + jbase + sch * 8;
    ushort_t* pDst = pLds + prow * 72 + pjc * 4;

    f32x4 acc[2][4];
#pragma unroll
    for (int mt = 0; mt < 2; ++mt)
#pragma unroll
        for (int nt = 0; nt < 4; ++nt) acc[mt][nt] = (f32x4){0.f, 0.f, 0.f, 0.f};
    float zacc = 0.f;

    // prefetch tile 0
    i32x4 Av = *(const i32x4*)aBase;
    f32x4 Sv = *(const f32x4*)sBase;
    u32x4 Wv[4];
#pragma unroll
    for (int r = 0; r < 4; ++r) Wv[r] = *(const u32x4*)(wBase + (size_t)r * 64 * 8192);

    for (int it = 0; it < iters; ++it) {
        const int jn = (it < iters - 1) ? (it + 1) * 64 : it * 64;
        i32x4 Ac = Av;
        f32x4 Sc = Sv;
        u32x4 Wc[4];
#pragma unroll
        for (int r = 0; r < 4; ++r) Wc[r] = Wv[r];
        // issue next-tile loads
        Av = *(const i32x4*)(aBase + jn);
        Sv = *(const f32x4*)(sBase + jn);
#pragma unroll
        for (int r = 0; r < 4; ++r) Wv[r] = *(const u32x4*)(wBase + (size_t)r * 64 * 8192 + jn);

        __syncthreads();  // prev MFMA reads done -> LDS writable
#pragma unroll
        for (int r = 0; r < 4; ++r)
            *(u32x4*)(wLds + (r * 64 + srow) * 72 + sch * 8) = Wc[r];
        {
            u16x4 pv4;
            float z4 = 0.f;
#pragma unroll
            for (int k = 0; k < 4; ++k) {
                float sc = ssrc + Sc[k] + ab;
                sc = sc > 0.f ? sc : LRELU_SLOPE * sc;
                sc = fminf(sc, 60.f);
                float pv = (Ac[k] > 0) ? __expf(sc) : 0.f;
                z4 += pv;
                pv4[k] = f2bf(pv);
            }
            zacc += z4;
            *(u16x4*)pDst = pv4;
        }
        __syncthreads();
        {
            short8 b[4];
#pragma unroll
            for (int nt = 0; nt < 4; ++nt)
                b[nt] = *(const short8*)(wLds + (dq * 64 + nt * 16 + (ln & 15)) * 72 + kh * 32 + (ln >> 4) * 8);
#pragma unroll
            for (int mt = 0; mt < 2; ++mt) {
                short8 a = *(const short8*)(pLds + (mt * 16 + (ln & 15)) * 72 + kh * 32 + (ln >> 4) * 8);
#pragma unroll
                for (int nt = 0; nt < 4; ++nt)
                    acc[mt][nt] = __builtin_amdgcn_mfma_f32_16x16x32_bf16(a, b[nt], acc[mt][nt], 0, 0, 0);
            }
        }
    }

    // per-row Z from the 16 consecutive lanes of each prow group
    zacc += __shfl_xor(zacc, 1, 64);
    zacc += __shfl_xor(zacc, 2, 64);
    zacc += __shfl_xor(zacc, 4, 64);
    zacc += __shfl_xor(zacc, 8, 64);
    if (split2) {
        if ((t & 15) == 0) zp[(size_t)jb * 8192 + i0 + prow] = zacc;
    } else {
        if ((t & 15) == 0) zLds[prow] = 1.0f / fmaxf(zacc, 1e-30f);
    }

    __syncthreads();  // all MFMA LDS reads done; wLds reusable as exchange
    float* ex = (float*)wLds;  // stride-33: conflict-free
    if (kh == 1) {
        float* p = ex + (dq * 64 + ln) * 33;
#pragma unroll
        for (int mt = 0; mt < 2; ++mt)
#pragma unroll
            for (int nt = 0; nt < 4; ++nt)
#pragma unroll
                for (int r = 0; r < 4; ++r) p[mt * 16 + nt * 4 + r] = acc[mt][nt][r];
    }
    __syncthreads();
    if (kh == 0) {
        float* outp = (jb == 0) ? out0 : out1;
        const float* p = ex + (dq * 64 + ln) * 33;
#pragma unroll
        for (int mt = 0; mt < 2; ++mt)
#pragma unroll
            for (int nt = 0; nt < 4; ++nt)
#pragma unroll
                for (int r = 0; r < 4; ++r) {
                    const int il = mt * 16 + (ln >> 4) * 4 + r;
                    const int d = dq * 64 + nt * 16 + (ln & 15);
                    const float v = acc[mt][nt][r] + p[mt * 16 + nt * 4 + r];
                    if (split2)
                        outp[(size_t)(i0 + il) * 256 + d] = v;
                    else
                        outp[(size_t)(i0 + il) * 256 + d] = v * zLds[il];
                }
    }
}

// ---------------------------------------------------------------------------
// K3 (jsplit==2 only): out = (out + part) / (z0 + z1). grid 8192 x 256.
// ---------------------------------------------------------------------------
__global__ void k3_norm(float* __restrict__ out, const float* __restrict__ part,
                        const float* __restrict__ zp) {
    const int i = blockIdx.x, t = threadIdx.x;
    const float rz = 1.0f / fmaxf(zp[i] + zp[8192 + i], 1e-30f);
    const size_t idx = (size_t)i * 256 + t;
    out[idx] = (out[idx] + part[idx]) * rz;
}

extern "C" void kernel_launch(void* const* d_in, const int* in_sizes, int n_in, void* d_out,
                              int out_size, void* d_ws, size_t ws_size, hipStream_t stream) {
    // identify inputs by flat size (validated r7/r8)
    int order[16];
    for (int i = 0; i < n_in; ++i) order[i] = i;
    for (int a = 0; a < n_in; ++a)
        for (int b = a + 1; b < n_in; ++b)
            if (in_sizes[order[b]] < in_sizes[order[a]]) {
                int tmp = order[a]; order[a] = order[b]; order[b] = tmp;
            }
    const float* ab = (const float*)d_in[order[0]];
    const float* Wb = (const float*)d_in[order[1]];
    const float* aw = (const float*)d_in[order[2]];
    const float* Ww = (const float*)d_in[order[3]];
    const float* h = (const float*)d_in[order[4]];
    const int* adj = (const int*)d_in[order[5]];

    char* ws = (char*)d_ws;
    ushort_t* whT = (ushort_t*)ws;                 // 4 MB
    float* ssrc = (float*)(ws + 4194304);          // 32 KB
    float* sdst = (float*)(ws + 4227072);          // 32 KB
    float* part = (float*)(ws + 4259840);          // 8 MB (jb=1 partial)
    float* zp = (float*)(ws + 12648448);           // 64 KB (2 x 8192 f32)
    const size_t need = 12713984;
    const int jsplit = (ws_size >= need) ? 2 : 1;

    hipLaunchKernelGGL(k1_gemm, dim3(256), dim3(256), 0, stream, h, Ww, Wb, aw, whT, ssrc, sdst);
    hipLaunchKernelGGL(k2_attn, dim3(256 * jsplit), dim3(512), 0, stream, adj, whT, ssrc, sdst,
                       ab, (float*)d_out, part, zp, jsplit);
    if (jsplit == 2)
        hipLaunchKernelGGL(k3_norm, dim3(8192), dim3(256), 0, stream, (float*)d_out, part, zp);
}